// Round 2
// baseline (1749.000 us; speedup 1.0000x reference)
//
#include <hip/hip_runtime.h>
#include <math.h>

#define N_NODES 50000
#define N_EDGES 800000
#define IN_FEATS 128
#define HEADS 4
#define HIDDEN 32
#define N_GRAPHS 64
#define NEG_SLOPE 0.2f

// monotone float<->uint key for atomicMax-based segment max.
// key==0 is smaller than key(x) for any finite float x.
__device__ __forceinline__ unsigned fkey(float f) {
    unsigned u = __float_as_uint(f);
    return (u & 0x80000000u) ? ~u : (u | 0x80000000u);
}
__device__ __forceinline__ float kval(unsigned k) {
    unsigned u = (k & 0x80000000u) ? (k & 0x7FFFFFFFu) : ~k;
    return __uint_as_float(u);
}

// h0[n,:] = embeds[word_ids[n],:]  (float4 vectorized; 128 f32 per row)
__global__ void gather_kernel(const int* __restrict__ wid, const float4* __restrict__ emb4,
                              float4* __restrict__ h4) {
    int i = blockIdx.x * 256 + threadIdx.x;   // N*32 threads exactly
    int n = i >> 5, q = i & 31;
    h4[i] = emb4[wid[n] * 32 + q];
}

// feat = h @ W (128x128), el/er = head-wise dot with al/ar.
// block = 256 threads = 2 nodes x 128 cols.
__global__ void feat_kernel(const float* __restrict__ h, const float* __restrict__ W,
                            const float* __restrict__ al, const float* __restrict__ ar,
                            float* __restrict__ feat, float* __restrict__ el,
                            float* __restrict__ er) {
    __shared__ float hs[2][128];
    int tid = threadIdx.x;
    int ln = tid >> 7;          // local node 0/1
    int c = tid & 127;
    int n = blockIdx.x * 2 + ln;
    hs[ln][c] = h[n * 128 + c];
    __syncthreads();
    float a0 = 0.f, a1 = 0.f, a2 = 0.f, a3 = 0.f;
    #pragma unroll
    for (int k = 0; k < 128; k += 4) {
        a0 += hs[ln][k + 0] * W[(k + 0) * 128 + c];
        a1 += hs[ln][k + 1] * W[(k + 1) * 128 + c];
        a2 += hs[ln][k + 2] * W[(k + 2) * 128 + c];
        a3 += hs[ln][k + 3] * W[(k + 3) * 128 + c];
    }
    float acc = (a0 + a1) + (a2 + a3);
    feat[n * 128 + c] = acc;
    float pl = acc * al[c];
    float pr = acc * ar[c];
    // reduce within 32-lane head groups (wave = 64 consecutive c of one node)
    #pragma unroll
    for (int off = 16; off; off >>= 1) {
        pl += __shfl_down(pl, off, 32);
        pr += __shfl_down(pr, off, 32);
    }
    if ((c & 31) == 0) {
        int hd = c >> 5;
        el[n * 4 + hd] = pl;
        er[n * 4 + hd] = pr;
    }
}

// e = leaky_relu(el[src] + er[dst]); store e; atomicMax segment-max keys at dst
__global__ void edge_e_kernel(const int* __restrict__ src, const int* __restrict__ dst,
                              const float4* __restrict__ el4, const float4* __restrict__ er4,
                              float4* __restrict__ ebuf, unsigned* __restrict__ mkeys) {
    int e = blockIdx.x * 256 + threadIdx.x;
    if (e >= N_EDGES) return;
    int s = src[e], d = dst[e];
    float4 l = el4[s], r = er4[d];
    float4 v;
    v.x = l.x + r.x; v.x = v.x > 0.f ? v.x : NEG_SLOPE * v.x;
    v.y = l.y + r.y; v.y = v.y > 0.f ? v.y : NEG_SLOPE * v.y;
    v.z = l.z + r.z; v.z = v.z > 0.f ? v.z : NEG_SLOPE * v.z;
    v.w = l.w + r.w; v.w = v.w > 0.f ? v.w : NEG_SLOPE * v.w;
    ebuf[e] = v;
    unsigned* mk = mkeys + d * 4;
    atomicMax(mk + 0, fkey(v.x));
    atomicMax(mk + 1, fkey(v.y));
    atomicMax(mk + 2, fkey(v.z));
    atomicMax(mk + 3, fkey(v.w));
}

// ex = exp(e - m[dst]); store ex; atomicAdd into denom[dst]
__global__ void edge_exp_kernel(const int* __restrict__ dst, float4* __restrict__ ebuf,
                                const uint4* __restrict__ mkeys4, float* __restrict__ denom) {
    int e = blockIdx.x * 256 + threadIdx.x;
    if (e >= N_EDGES) return;
    int d = dst[e];
    float4 v = ebuf[e];
    uint4 mk = mkeys4[d];
    v.x = expf(v.x - kval(mk.x));
    v.y = expf(v.y - kval(mk.y));
    v.z = expf(v.z - kval(mk.z));
    v.w = expf(v.w - kval(mk.w));
    ebuf[e] = v;
    float* dn = denom + d * 4;
    atomicAdd(dn + 0, v.x);
    atomicAdd(dn + 1, v.y);
    atomicAdd(dn + 2, v.z);
    atomicAdd(dn + 3, v.w);
}

// out[dst, c] += feat[src, c] * alpha[e, c>>5]  — one thread per (edge, c)
__global__ void message_kernel(const int* __restrict__ src, const int* __restrict__ dst,
                               const float* __restrict__ feat, const float* __restrict__ ebuf,
                               const float* __restrict__ denom, float* __restrict__ out) {
    int i = blockIdx.x * 256 + threadIdx.x;   // E*128 = 102.4M exact
    int e = i >> 7, c = i & 127;
    int s = src[e], d = dst[e];
    int hd = c >> 5;
    float ex = ebuf[e * 4 + hd];
    float dn = denom[d * 4 + hd];
    float alpha = ex / (dn + 1e-10f);
    atomicAdd(out + d * 128 + c, feat[s * 128 + c] * alpha);
}

__global__ void elu_kernel(float* __restrict__ x) {
    int i = blockIdx.x * 256 + threadIdx.x;   // N*128 = 6.4M exact
    float v = x[i];
    x[i] = v > 0.f ? v : expm1f(v);
}

__global__ void pool_kernel(const int* __restrict__ gid, const float* __restrict__ h,
                            unsigned* __restrict__ pkeys) {
    int i = blockIdx.x * 256 + threadIdx.x;   // N*128
    int n = i >> 7, c = i & 127;
    atomicMax(pkeys + gid[n] * 128 + c, fkey(h[i]));
}

// logits[g] = sum_c pooled[g,c]*w[c] + b ; empty-graph guard via key==0 -> 0
__global__ void logits_kernel(const unsigned* __restrict__ pkeys, const float* __restrict__ w,
                              const float* __restrict__ bptr, float* __restrict__ logits) {
    int g = blockIdx.x, t = threadIdx.x;      // 64 blocks x 64 threads
    float sum = 0.f;
    for (int c = t; c < 128; c += 64) {
        unsigned k = pkeys[g * 128 + c];
        float v = (k == 0u) ? 0.f : kval(k);
        sum += v * w[c];
    }
    #pragma unroll
    for (int off = 32; off; off >>= 1) sum += __shfl_down(sum, off, 64);
    if (t == 0) logits[g] = sum + bptr[0];
}

__global__ void final_kernel(const float* __restrict__ logits, const float* __restrict__ y,
                             float* __restrict__ out) {
    int t = threadIdx.x;  // 64
    float l = logits[t];
    float yy = y[t];
    float term = fmaxf(l, 0.f) - l * yy + log1pf(expf(-fabsf(l)));
    float s = term;
    #pragma unroll
    for (int off = 32; off; off >>= 1) s += __shfl_down(s, off, 64);
    out[1 + t] = 1.f / (1.f + expf(-l));
    if (t == 0) out[0] = s * (1.f / 64.f);
}

extern "C" void kernel_launch(void* const* d_in, const int* in_sizes, int n_in,
                              void* d_out, int out_size, void* d_ws, size_t ws_size,
                              hipStream_t stream) {
    const int* word_ids  = (const int*)d_in[0];
    const int* esrc      = (const int*)d_in[1];
    const int* edst      = (const int*)d_in[2];
    const int* gid       = (const int*)d_in[3];
    const float* y_data  = (const float*)d_in[4];
    const float* emb     = (const float*)d_in[5];
    const float* W0      = (const float*)d_in[6];
    const float* al0     = (const float*)d_in[7];
    const float* ar0     = (const float*)d_in[8];
    const float* W1      = (const float*)d_in[9];
    const float* al1     = (const float*)d_in[10];
    const float* ar1     = (const float*)d_in[11];
    const float* out_w   = (const float*)d_in[12];
    const float* out_b   = (const float*)d_in[13];
    float* out = (float*)d_out;

    // workspace layout (float offsets); total ~67.3 MB
    float* ws = (float*)d_ws;
    float*    feat  = ws;                          // N*128 = 6,400,000
    float*    hbuf  = ws + 6400000;                // N*128 (in/out aliased per layer)
    float*    el    = ws + 12800000;               // N*4
    float*    er    = ws + 13000000;               // N*4
    unsigned* mkeys = (unsigned*)(ws + 13200000);  // N*4
    float*    denom = ws + 13400000;               // N*4
    float*    ebuf  = ws + 13600000;               // E*4
    unsigned* pkeys = (unsigned*)(ws + 16800000);  // 64*128
    float*    logits= ws + 16808192;               // 64

    gather_kernel<<<6250, 256, 0, stream>>>(word_ids, (const float4*)emb, (float4*)hbuf);

    auto layer = [&](const float* W, const float* al, const float* ar) {
        // feat/el/er from current hbuf; hbuf is dead afterwards -> becomes hout
        feat_kernel<<<25000, 256, 0, stream>>>(hbuf, W, al, ar, feat, el, er);
        hipMemsetAsync(mkeys, 0, (size_t)N_NODES * 4 * 4, stream);
        hipMemsetAsync(denom, 0, (size_t)N_NODES * 4 * 4, stream);
        hipMemsetAsync(hbuf, 0, (size_t)N_NODES * 128 * 4, stream);
        edge_e_kernel<<<3125, 256, 0, stream>>>(esrc, edst, (const float4*)el,
                                                (const float4*)er, (float4*)ebuf, mkeys);
        edge_exp_kernel<<<3125, 256, 0, stream>>>(edst, (float4*)ebuf,
                                                  (const uint4*)mkeys, denom);
        message_kernel<<<400000, 256, 0, stream>>>(esrc, edst, feat, ebuf, denom, hbuf);
        elu_kernel<<<25000, 256, 0, stream>>>(hbuf);
    };

    layer(W0, al0, ar0);
    layer(W1, al1, ar1);

    hipMemsetAsync(pkeys, 0, (size_t)N_GRAPHS * 128 * 4, stream);
    pool_kernel<<<25000, 256, 0, stream>>>(gid, hbuf, pkeys);
    logits_kernel<<<N_GRAPHS, 64, 0, stream>>>(pkeys, out_w, out_b, logits);
    final_kernel<<<1, 64, 0, stream>>>(logits, y_data, out);
}

// Round 3
// 648.465 us; speedup vs baseline: 2.6971x; 2.6971x over previous
//
#include <hip/hip_runtime.h>
#include <math.h>

#define N_NODES 50000
#define N_EDGES 800000
#define HEADS 4
#define N_GRAPHS 64
#define NEG_SLOPE 0.2f

// monotone float<->uint key for atomicMax-based segment max (pooling).
// key==0 is smaller than key(x) for any finite float x.
__device__ __forceinline__ unsigned fkey(float f) {
    unsigned u = __float_as_uint(f);
    return (u & 0x80000000u) ? ~u : (u | 0x80000000u);
}
__device__ __forceinline__ float kval(unsigned k) {
    unsigned u = (k & 0x80000000u) ? (k & 0x7FFFFFFFu) : ~k;
    return __uint_as_float(u);
}

// ---------------- CSR build (counting sort by dst) ----------------

__global__ void hist_kernel(const int* __restrict__ dst, int* __restrict__ deg) {
    int e = blockIdx.x * 256 + threadIdx.x;
    if (e < N_EDGES) atomicAdd(&deg[dst[e]], 1);
}

// single-block exclusive scan of deg[N_NODES] -> row_start[N_NODES+1], copy to cursor
__global__ void scan_kernel(const int* __restrict__ deg, int* __restrict__ row_start,
                            int* __restrict__ cursor) {
    __shared__ int buf[1024];
    __shared__ int carry;
    int t = threadIdx.x;
    if (t == 0) carry = 0;
    __syncthreads();
    for (int base = 0; base < N_NODES; base += 1024) {
        int i = base + t;
        int v = (i < N_NODES) ? deg[i] : 0;
        buf[t] = v;
        __syncthreads();
        #pragma unroll
        for (int off = 1; off < 1024; off <<= 1) {
            int add = (t >= off) ? buf[t - off] : 0;
            __syncthreads();
            buf[t] += add;
            __syncthreads();
        }
        int excl = buf[t] - v + carry;
        if (i < N_NODES) { row_start[i] = excl; cursor[i] = excl; }
        __syncthreads();                 // everyone has read carry
        if (t == 0) carry += buf[1023];
        __syncthreads();
    }
    if (t == 0) row_start[N_NODES] = carry;   // == N_EDGES
}

__global__ void scatter_kernel(const int* __restrict__ src, const int* __restrict__ dst,
                               int* __restrict__ cursor, int* __restrict__ csr_src) {
    int e = blockIdx.x * 256 + threadIdx.x;
    if (e < N_EDGES) {
        int p = atomicAdd(&cursor[dst[e]], 1);
        csr_src[p] = src[e];
    }
}

// ---------------- node pipeline ----------------

// h0[n,:] = embeds[word_ids[n],:]  (float4; 32 float4 per row)
__global__ void gather_kernel(const int* __restrict__ wid, const float4* __restrict__ emb4,
                              float4* __restrict__ h4) {
    int i = blockIdx.x * 256 + threadIdx.x;   // N*32 threads exactly
    int n = i >> 5, q = i & 31;
    h4[i] = emb4[wid[n] * 32 + q];
}

// feat = h @ W (128x128) with W staged in LDS; el/er head dots fused.
// 256 threads, 16 nodes per block, grid = 3125.
__global__ void feat_kernel(const float* __restrict__ h, const float* __restrict__ W,
                            const float* __restrict__ al, const float* __restrict__ ar,
                            float* __restrict__ feat, float* __restrict__ el,
                            float* __restrict__ er) {
    __shared__ float Wl[128 * 128];      // 64 KB
    __shared__ float hl[16][128];        // 8 KB
    int t = threadIdx.x;
    {   // stage W: 4096 float4 / 256 threads = 16 each
        const float4* W4 = (const float4*)W;
        float4* Wl4 = (float4*)Wl;
        #pragma unroll
        for (int i = 0; i < 16; ++i) Wl4[t + 256 * i] = W4[t + 256 * i];
    }
    int n0 = blockIdx.x * 16;
    {   // stage h tile: 512 float4 / 256 threads = 2 each
        const float4* h4 = (const float4*)(h + (size_t)n0 * 128);
        float4* hl4 = (float4*)hl;
        hl4[t] = h4[t];
        hl4[t + 256] = h4[t + 256];
    }
    __syncthreads();
    int cg = (t & 31) * 4;       // channel group (4 consecutive channels)
    int nl = t >> 5;             // local node 0..7
    int hd = (t & 31) >> 3;      // head of this channel group
    float al0 = al[cg], al1 = al[cg + 1], al2 = al[cg + 2], al3 = al[cg + 3];
    float ar0 = ar[cg], ar1 = ar[cg + 1], ar2 = ar[cg + 2], ar3 = ar[cg + 3];
    #pragma unroll
    for (int rep = 0; rep < 2; ++rep) {
        int n = nl + 8 * rep;
        float4 acc = {0.f, 0.f, 0.f, 0.f};
        #pragma unroll 16
        for (int k = 0; k < 128; ++k) {
            float hv = hl[n][k];
            float4 w4 = *(const float4*)&Wl[k * 128 + cg];
            acc.x += hv * w4.x; acc.y += hv * w4.y;
            acc.z += hv * w4.z; acc.w += hv * w4.w;
        }
        *(float4*)(feat + (size_t)(n0 + n) * 128 + cg) = acc;
        float pl = acc.x * al0 + acc.y * al1 + acc.z * al2 + acc.w * al3;
        float pr = acc.x * ar0 + acc.y * ar1 + acc.z * ar2 + acc.w * ar3;
        // reduce over the 8 threads covering one head (contiguous lanes, same wave)
        #pragma unroll
        for (int off = 1; off < 8; off <<= 1) {
            pl += __shfl_xor(pl, off, 64);
            pr += __shfl_xor(pr, off, 64);
        }
        if ((t & 7) == 0) {
            el[(n0 + n) * 4 + hd] = pl;
            er[(n0 + n) * 4 + hd] = pr;
        }
    }
}

// Fused softmax + aggregation + ELU. One 64-lane wave per dst node.
// 256 threads = 4 waves = 4 nodes per block; grid = 12500.
// Softmax computed without max-subtraction (invariant; |e| is O(1) here).
__global__ void gat_aggregate(const int* __restrict__ row_start, const int* __restrict__ csr_src,
                              const float* __restrict__ feat, const float* __restrict__ el,
                              const float* __restrict__ er, float* __restrict__ hout) {
    int lane = threadIdx.x & 63;
    int d = blockIdx.x * 4 + (threadIdx.x >> 6);
    int beg = row_start[d], end = row_start[d + 1];
    int j = lane >> 2;           // edge slot 0..15
    int h = lane & 3;            // head (for ex phase)
    float er_h = er[d * 4 + h];
    int hc = lane >> 4;          // head of this lane's channel pair (c=2*lane,2*lane+1)
    float accx = 0.f, accy = 0.f, dsum = 0.f;
    for (int base = beg; base < end; base += 16) {
        int idx = base + j;
        bool valid = idx < end;
        int s = csr_src[valid ? idx : beg];
        float ev = el[s * 4 + h] + er_h;
        ev = ev > 0.f ? ev : NEG_SLOPE * ev;
        float ex = valid ? __expf(ev) : 0.f;
        dsum += ex;
        int cnt = min(16, end - base);
        for (int jj = 0; jj < cnt; ++jj) {
            int   sj  = __shfl(s,  jj * 4, 64);
            float exj = __shfl(ex, jj * 4 + hc, 64);
            float2 f = ((const float2*)(feat + (size_t)sj * 128))[lane];
            accx += f.x * exj;
            accy += f.y * exj;
        }
    }
    // denom per head: sum over lanes sharing (lane & 3)
    #pragma unroll
    for (int off = 4; off < 64; off <<= 1) dsum += __shfl_xor(dsum, off, 64);
    float dh = __shfl(dsum, hc, 64);     // lane 'hc' holds denom of head hc
    float inv = 1.f / (dh + 1e-10f);
    float ox = accx * inv, oy = accy * inv;
    ox = ox > 0.f ? ox : expm1f(ox);
    oy = oy > 0.f ? oy : expm1f(oy);
    float2 o = {ox, oy};
    ((float2*)(hout + (size_t)d * 128))[lane] = o;
}

// ---------------- pooling / loss ----------------

__global__ void pool_kernel(const int* __restrict__ gid, const float* __restrict__ h,
                            unsigned* __restrict__ pkeys) {
    int i = blockIdx.x * 256 + threadIdx.x;   // N*128
    int n = i >> 7, c = i & 127;
    atomicMax(pkeys + gid[n] * 128 + c, fkey(h[i]));
}

__global__ void logits_kernel(const unsigned* __restrict__ pkeys, const float* __restrict__ w,
                              const float* __restrict__ bptr, float* __restrict__ logits) {
    int g = blockIdx.x, t = threadIdx.x;      // 64 blocks x 64 threads
    float sum = 0.f;
    for (int c = t; c < 128; c += 64) {
        unsigned k = pkeys[g * 128 + c];
        float v = (k == 0u) ? 0.f : kval(k);
        sum += v * w[c];
    }
    #pragma unroll
    for (int off = 32; off; off >>= 1) sum += __shfl_down(sum, off, 64);
    if (t == 0) logits[g] = sum + bptr[0];
}

__global__ void final_kernel(const float* __restrict__ logits, const float* __restrict__ y,
                             float* __restrict__ out) {
    int t = threadIdx.x;  // 64
    float l = logits[t];
    float term = fmaxf(l, 0.f) - l * y[t] + log1pf(expf(-fabsf(l)));
    float s = term;
    #pragma unroll
    for (int off = 32; off; off >>= 1) s += __shfl_down(s, off, 64);
    out[1 + t] = 1.f / (1.f + expf(-l));
    if (t == 0) out[0] = s * (1.f / 64.f);
}

extern "C" void kernel_launch(void* const* d_in, const int* in_sizes, int n_in,
                              void* d_out, int out_size, void* d_ws, size_t ws_size,
                              hipStream_t stream) {
    const int* word_ids  = (const int*)d_in[0];
    const int* esrc      = (const int*)d_in[1];
    const int* edst      = (const int*)d_in[2];
    const int* gid       = (const int*)d_in[3];
    const float* y_data  = (const float*)d_in[4];
    const float* emb     = (const float*)d_in[5];
    const float* W0      = (const float*)d_in[6];
    const float* al0     = (const float*)d_in[7];
    const float* ar0     = (const float*)d_in[8];
    const float* W1      = (const float*)d_in[9];
    const float* al1     = (const float*)d_in[10];
    const float* ar1     = (const float*)d_in[11];
    const float* out_w   = (const float*)d_in[12];
    const float* out_b   = (const float*)d_in[13];
    float* out = (float*)d_out;

    // workspace layout (float offsets); ~57 MB total
    float* ws = (float*)d_ws;
    float*    feat   = ws;                           // 6,400,000
    float*    hbuf   = ws + 6400000;                 // 6,400,000
    float*    el     = ws + 12800000;                // 200,000
    float*    er     = ws + 13000000;                // 200,000
    int*      row_st = (int*)(ws + 13200000);        // 50,001
    int*      deg    = (int*)(ws + 13251000);        // 50,000
    int*      cursor = (int*)(ws + 13301000);        // 50,000
    int*      csrsrc = (int*)(ws + 13351000);        // 800,000
    unsigned* pkeys  = (unsigned*)(ws + 14151000);   // 8,192
    float*    logits = ws + 14159192;                // 64

    // CSR build (shared by both layers)
    hipMemsetAsync(deg, 0, (size_t)N_NODES * 4, stream);
    hist_kernel<<<3125, 256, 0, stream>>>(edst, deg);
    scan_kernel<<<1, 1024, 0, stream>>>(deg, row_st, cursor);
    scatter_kernel<<<3125, 256, 0, stream>>>(esrc, edst, cursor, csrsrc);

    gather_kernel<<<6250, 256, 0, stream>>>(word_ids, (const float4*)emb, (float4*)hbuf);

    auto layer = [&](const float* W, const float* al, const float* ar) {
        feat_kernel<<<3125, 256, 0, stream>>>(hbuf, W, al, ar, feat, el, er);
        gat_aggregate<<<12500, 256, 0, stream>>>(row_st, csrsrc, feat, el, er, hbuf);
    };
    layer(W0, al0, ar0);
    layer(W1, al1, ar1);

    hipMemsetAsync(pkeys, 0, (size_t)N_GRAPHS * 128 * 4, stream);
    pool_kernel<<<25000, 256, 0, stream>>>(gid, hbuf, pkeys);
    logits_kernel<<<N_GRAPHS, 64, 0, stream>>>(pkeys, out_w, out_b, logits);
    final_kernel<<<1, 64, 0, stream>>>(logits, y_data, out);
}